// Round 17
// baseline (1395.354 us; speedup 1.0000x reference)
//
#include <hip/hip_runtime.h>
#include <hip/hip_bf16.h>
#include <cstdint>
#include <cstddef>

// ---------------------------------------------------------------------------
// Transformer encoder, 6 layers: B=2,S=2048,D=1024,H=16,HD=64,F=4096.
// Weight transposes hoisted to ONE up-front dispatch (ws-size guarded).
// QKV: 256x192-tile (grid 256 = 1/CU), V written directly transposed.
// FFN1: 256^2. Both: 8-wave counted-vmcnt double buffer (T2+T3+T4+T5).
// FFN2: gemm256 split-K=4 + fused LN. O-proj: 128^2 pipeline.
// Flash attention: 16-wave blocks (Q=256), KVBLK=128, XCD-swizzled grid,
// swapped QK^T, T2 swizzle, reg-staged K/V double buffer.
// ---------------------------------------------------------------------------

typedef __bf16 bf16;
typedef __bf16 bf16x2 __attribute__((ext_vector_type(2)));
typedef __bf16 bf16x4 __attribute__((ext_vector_type(4)));
typedef __bf16 bf16x8 __attribute__((ext_vector_type(8)));
typedef float  f32x4  __attribute__((ext_vector_type(4)));

#define MFMA16(a, b, c) __builtin_amdgcn_mfma_f32_16x16x32_bf16((a), (b), (c), 0, 0, 0)

static __device__ __forceinline__ void load_lds16(const void* g, void* l) {
  __builtin_amdgcn_global_load_lds((const __attribute__((address_space(1))) void*)g,
                                   (__attribute__((address_space(3))) void*)l, 16, 0, 0);
}

#define BAR()   __builtin_amdgcn_s_barrier()
#define SCH0()  __builtin_amdgcn_sched_barrier(0)
#define VMCNT8() asm volatile("s_waitcnt vmcnt(8)" ::: "memory")
#define VMCNT7() asm volatile("s_waitcnt vmcnt(7)" ::: "memory")
#define VMCNT0() asm volatile("s_waitcnt vmcnt(0)" ::: "memory")

// ---------------- embedding + positional encoding -> bf16 x ----------------
__global__ __launch_bounds__(256) void embed_kernel(const int* __restrict__ tok,
                                                    const float* __restrict__ emb,
                                                    bf16* __restrict__ xo) {
  const int row = blockIdx.x;          // b*2048 + s
  const int s = row & 2047;
  const int t = tok[row];
  const int d0 = threadIdx.x * 4;
  const float4 e = *(const float4*)&emb[(size_t)t * 1024 + d0];
  const float* ef = (const float*)&e;
  bf16x4 o4;
#pragma unroll
  for (int j = 0; j < 4; ++j) {
    const int d = d0 + j;
    const float div = __expf(-(float)(d & ~1) * 0.00899447301950864f); // ln(1e4)/1024
    const float arg = (float)s * div;
    const float pe = (d & 1) ? cosf(arg) : sinf(arg);
    o4[j] = (bf16)(ef[j] + pe);
  }
  *(bf16x4*)&xo[(size_t)row * 1024 + d0] = o4;
}

// ------------- weight transpose: fp32 [K][N] -> bf16 [N][K] -----------------
// 3072 blocks per layer: [0,768) QKV (256 each), [768,1024) Wo,
// [1024,2048) W1 (K=1024,N=4096), [2048,3072) W2 (K=4096,N=1024).
// layer = blockIdx.x / 3072 (0 for per-layer fallback launches).
__global__ __launch_bounds__(256) void wtrans_all(
    const float* __restrict__ Wq, const float* __restrict__ Wk,
    const float* __restrict__ Wv, const float* __restrict__ Wo,
    const float* __restrict__ W1, const float* __restrict__ W2,
    bf16* __restrict__ dqkv, bf16* __restrict__ dow,
    bf16* __restrict__ d1, bf16* __restrict__ d2,
    long qkvStride, long oStride, long s1, long s2) {
  __shared__ float t[64][65];
  const int layer = blockIdx.x / 3072;
  const int r = blockIdx.x - layer * 3072;
  const float* src; bf16* dst; int K, N, tj;
  if (r < 768) {
    const int seg = r >> 8;                    // 0=q,1=k,2=v
    const float* S = (seg == 0) ? Wq : (seg == 1) ? Wk : Wv;
    src = S + (size_t)layer * 1024 * 1024;
    dst = dqkv + (size_t)layer * qkvStride + (size_t)seg * 1024 * 1024;
    K = 1024; N = 1024; tj = r & 255;
  } else if (r < 1024) {
    src = Wo + (size_t)layer * 1024 * 1024;
    dst = dow + (size_t)layer * oStride;
    K = 1024; N = 1024; tj = r - 768;
  } else if (r < 2048) {
    src = W1 + (size_t)layer * 1024 * 4096;
    dst = d1 + (size_t)layer * s1;
    K = 1024; N = 4096; tj = r - 1024;
  } else {
    src = W2 + (size_t)layer * 4096 * 1024;
    dst = d2 + (size_t)layer * s2;
    K = 4096; N = 1024; tj = r - 2048;
  }
  const int tilesK = K >> 6;
  const int tk = (tj % tilesK) << 6;
  const int tn = (tj / tilesK) << 6;
  const int tid = threadIdx.x;
  const int rr = tid >> 4;            // 0..15
  const int c4 = (tid & 15) * 4;
#pragma unroll
  for (int i = 0; i < 4; ++i) {
    const float4 v = *(const float4*)&src[(size_t)(tk + rr + 16 * i) * N + tn + c4];
    t[rr + 16 * i][c4 + 0] = v.x;
    t[rr + 16 * i][c4 + 1] = v.y;
    t[rr + 16 * i][c4 + 2] = v.z;
    t[rr + 16 * i][c4 + 3] = v.w;
  }
  __syncthreads();
  const int k0 = (tid & 15) * 4;
#pragma unroll
  for (int i = 0; i < 4; ++i) {
    const int n = rr + 16 * i;
    bf16x4 o;
#pragma unroll
    for (int j = 0; j < 4; ++j) o[j] = (bf16)t[k0 + j][n];
    *(bf16x4*)&dst[(size_t)(tn + n) * K + tk + k0] = o;
  }
}

// ======================= shared GEMM building blocks ========================
static __device__ __forceinline__ bf16x8 ldsfrag(const bf16* base, int row, int colb) {
  int off = row * 128 + colb;
  off ^= ((off >> 7) & 7) << 4;
  return *(const bf16x8*)((const char*)base + off);
}

// ====== 256xBN-tile 8-wave GEMM, counted-vmcnt (BN = 64*BNF, BNF=3|4) ======
template <int BNF>
static __device__ __forceinline__ void stage_tileT(const bf16* __restrict__ Ag,
    const bf16* __restrict__ Bg, int Kstr, int kt, bf16* lA, bf16* lB, int tid) {
  const char* wbaseA = (const char*)lA + ((tid >> 6) << 10);
  const char* wbaseB = (const char*)lB + ((tid >> 6) << 10);
#pragma unroll
  for (int s = 0; s < 4; ++s) {
    const int L = s * 8192 + tid * 16;
    const int off = L ^ (((L >> 7) & 7) << 4);
    load_lds16(Ag + (size_t)(off >> 7) * Kstr + kt * 64 + ((off & 127) >> 1),
               (void*)(wbaseA + s * 8192));
  }
#pragma unroll
  for (int s = 0; s < BNF; ++s) {
    const int L = s * 8192 + tid * 16;
    const int off = L ^ (((L >> 7) & 7) << 4);
    load_lds16(Bg + (size_t)(off >> 7) * Kstr + kt * 64 + ((off & 127) >> 1),
               (void*)(wbaseB + s * 8192));
  }
}

template <int BNF>
static __device__ __forceinline__ void compute_tileT(const bf16* lA, const bf16* lB,
    int wm, int wn, int lr, int lg, f32x4 (&acc)[8][BNF]) {
  bf16x8 bfr[BNF][2];
#pragma unroll
  for (int n = 0; n < BNF; ++n)
#pragma unroll
    for (int kk = 0; kk < 2; ++kk)
      bfr[n][kk] = ldsfrag(lB, wn * (16 * BNF) + n * 16 + lr, kk * 64 + lg * 16);
#pragma unroll
  for (int m = 0; m < 8; ++m) {
    const bf16x8 a0 = ldsfrag(lA, wm * 128 + m * 16 + lr, lg * 16);
    const bf16x8 a1 = ldsfrag(lA, wm * 128 + m * 16 + lr, 64 + lg * 16);
    __builtin_amdgcn_s_setprio(1);
#pragma unroll
    for (int n = 0; n < BNF; ++n) {
      acc[m][n] = MFMA16(a0, bfr[n][0], acc[m][n]);
      acc[m][n] = MFMA16(a1, bfr[n][1], acc[m][n]);
    }
    __builtin_amdgcn_s_setprio(0);
  }
}

template <int BNF>
static __device__ __forceinline__ void waitK() {
  if constexpr (BNF == 3) { VMCNT7(); } else { VMCNT8(); }
}

template <int EPI, int BNF>  // EPI 0: qkv scatter (V transposed), 1: fp32 partial, 2: bias+relu
__global__ __launch_bounds__(512, 2) void gemm256(
    const bf16* __restrict__ A, const bf16* __restrict__ Bt,
    int Kstr, int Kloop, int Nn, int nbx,
    const float* __restrict__ bias0, const float* __restrict__ bias1,
    const float* __restrict__ bias2, bf16* __restrict__ outb,
    float* __restrict__ pout,
    bf16* __restrict__ q_out, bf16* __restrict__ k_out, bf16* __restrict__ vt_out) {
  __shared__ __align__(16) bf16 ldsA[2][16384];       // 32KB each
  __shared__ __align__(16) bf16 ldsB[2][BNF * 4096];  // BNF*8KB each
  const int bz = blockIdx.y;
  const bf16* Abase = A + (size_t)bz * Kloop;
  const bf16* Bbase = Bt + (size_t)bz * Kloop;
  const int cpx = gridDim.x >> 3;
  const int wg = (blockIdx.x & 7) * cpx + (blockIdx.x >> 3);
  const int bx = wg % nbx, by = wg / nbx;
  const int tid = threadIdx.x;
  const int lane = tid & 63, wave = tid >> 6;
  const int lr = lane & 15, lg = lane >> 4;
  const int wm = wave >> 2, wn = wave & 3;
  const int m0 = by * 256, n0 = bx * (64 * BNF);

  const bf16* Ag = Abase + (size_t)m0 * Kstr;
  const bf16* Bg = Bbase + (size_t)n0 * Kstr;

  f32x4 acc[8][BNF] = {};
  const int T = Kloop >> 6;

  stage_tileT<BNF>(Ag, Bg, Kstr, 0, ldsA[0], ldsB[0], tid);
  stage_tileT<BNF>(Ag, Bg, Kstr, 1, ldsA[1], ldsB[1], tid);
  waitK<BNF>(); BAR(); SCH0();

  for (int t = 0; t + 3 < T; t += 2) {
    compute_tileT<BNF>(ldsA[0], ldsB[0], wm, wn, lr, lg, acc);
    BAR(); SCH0();
    stage_tileT<BNF>(Ag, Bg, Kstr, t + 2, ldsA[0], ldsB[0], tid);
    waitK<BNF>(); BAR(); SCH0();
    compute_tileT<BNF>(ldsA[1], ldsB[1], wm, wn, lr, lg, acc);
    BAR(); SCH0();
    stage_tileT<BNF>(Ag, Bg, Kstr, t + 3, ldsA[1], ldsB[1], tid);
    waitK<BNF>(); BAR(); SCH0();
  }
  compute_tileT<BNF>(ldsA[0], ldsB[0], wm, wn, lr, lg, acc);  // tile T-2
  VMCNT0(); BAR(); SCH0();                                    // tile T-1 landed
  compute_tileT<BNF>(ldsA[1], ldsB[1], wm, wn, lr, lg, acc);  // tile T-1

#pragma unroll
  for (int m = 0; m < 8; ++m)
#pragma unroll
    for (int n = 0; n < BNF; ++n) {
      if (EPI == 0) {
        // col range of this fragment is 16-aligned -> segment-uniform
        const int col = n0 + wn * (16 * BNF) + n * 16 + lr;
        const int which = col >> 10, hc = col & 1023;
        const int h = hc >> 6, hd = hc & 63;
        const int row0 = m0 + wm * 128 + m * 16 + lg * 4;
        const int b = row0 >> 11, s0 = row0 & 2047;
        if (which == 2) {
          // V: 4 consecutive s at fixed hd -> one bf16x4 in [bh][hd][s] layout
          bf16x4 o;
#pragma unroll
          for (int r = 0; r < 4; ++r) o[r] = (bf16)(acc[m][n][r] + bias2[hc]);
          *(bf16x4*)&vt_out[(((size_t)b * 16 + h) * 64 + hd) * 2048 + s0] = o;
        } else {
          const float* bs = (which == 0) ? bias0 : bias1;
          bf16* dst = (which == 0) ? q_out : k_out;
#pragma unroll
          for (int r = 0; r < 4; ++r)
            dst[(((size_t)b * 16 + h) * 2048 + s0 + r) * 64 + hd] =
                (bf16)(acc[m][n][r] + bs[hc]);
        }
      } else {
#pragma unroll
        for (int r = 0; r < 4; ++r) {
          const int row = m0 + wm * 128 + m * 16 + lg * 4 + r;
          const int col = n0 + wn * (16 * BNF) + n * 16 + lr;
          float val = acc[m][n][r];
          if (EPI == 1) {
            pout[(size_t)bz * 4096 * 1024 + (size_t)row * 1024 + col] = val;
          } else {
            val += bias0[col];
            outb[(size_t)row * Nn + col] = (bf16)(val > 0.f ? val : 0.f);
          }
        }
      }
    }
}

// ========== 128x128-tile 4-wave GEMM, counted-vmcnt (O-proj K=1024) =========
static __device__ __forceinline__ void stage128(const bf16* __restrict__ Ag,
    const bf16* __restrict__ Bg, int Kstr, int kt, bf16* lA, bf16* lB, int tid) {
  const char* dA = (const char*)lA + ((tid >> 6) << 10);
  const char* dB = (const char*)lB + ((tid >> 6) << 10);
#pragma unroll
  for (int s = 0; s < 4; ++s) {
    const int L = s * 4096 + tid * 16;
    const int off = L ^ (((L >> 7) & 7) << 4);
    load_lds16(Ag + (size_t)(off >> 7) * Kstr + kt * 64 + ((off & 127) >> 1),
               (void*)(dA + s * 4096));
  }
#pragma unroll
  for (int s = 0; s < 4; ++s) {
    const int L = s * 4096 + tid * 16;
    const int off = L ^ (((L >> 7) & 7) << 4);
    load_lds16(Bg + (size_t)(off >> 7) * Kstr + kt * 64 + ((off & 127) >> 1),
               (void*)(dB + s * 4096));
  }
}

static __device__ __forceinline__ void compute128(const bf16* lA, const bf16* lB,
    int wm, int wn, int lr, int lg, f32x4 (&acc)[4][4]) {
  bf16x8 bfr[4][2];
#pragma unroll
  for (int n = 0; n < 4; ++n)
#pragma unroll
    for (int kk = 0; kk < 2; ++kk)
      bfr[n][kk] = ldsfrag(lB, wn * 64 + n * 16 + lr, kk * 64 + lg * 16);
#pragma unroll
  for (int m = 0; m < 4; ++m) {
    const bf16x8 a0 = ldsfrag(lA, wm * 64 + m * 16 + lr, lg * 16);
    const bf16x8 a1 = ldsfrag(lA, wm * 64 + m * 16 + lr, 64 + lg * 16);
    __builtin_amdgcn_s_setprio(1);
#pragma unroll
    for (int n = 0; n < 4; ++n) {
      acc[m][n] = MFMA16(a0, bfr[n][0], acc[m][n]);
      acc[m][n] = MFMA16(a1, bfr[n][1], acc[m][n]);
    }
    __builtin_amdgcn_s_setprio(0);
  }
}

__global__ __launch_bounds__(256, 2) void gemm128p(
    const bf16* __restrict__ A, const bf16* __restrict__ Bt, int Kk,
    const float* __restrict__ bias, const bf16* __restrict__ resid,
    float* __restrict__ outf) {
  __shared__ __align__(16) bf16 lds[4][8192];    // A0,B0,A1,B1 (16KB each)
  const int cpx = gridDim.x >> 3;
  const int wg = (blockIdx.x & 7) * cpx + (blockIdx.x >> 3);
  const int bx = wg & 7, by = wg >> 3;           // nbx = 8 (N=1024)
  const int tid = threadIdx.x;
  const int lane = tid & 63, wave = tid >> 6;
  const int lr = lane & 15, lg = lane >> 4;
  const int wm = wave >> 1, wn = wave & 1;
  const int m0 = by * 128, n0 = bx * 128;

  const bf16* Ag = A + (size_t)m0 * Kk;
  const bf16* Bg = Bt + (size_t)n0 * Kk;
  bf16* LA0 = lds[0]; bf16* LB0 = lds[1];
  bf16* LA1 = lds[2]; bf16* LB1 = lds[3];

  f32x4 acc[4][4] = {};
  const int T = Kk >> 6;

  stage128(Ag, Bg, Kk, 0, LA0, LB0, tid);
  stage128(Ag, Bg, Kk, 1, LA1, LB1, tid);
  VMCNT8(); BAR(); SCH0();

  for (int t = 0; t + 3 < T; t += 2) {
    compute128(LA0, LB0, wm, wn, lr, lg, acc);
    BAR(); SCH0();
    stage128(Ag, Bg, Kk, t + 2, LA0, LB0, tid);
    VMCNT8(); BAR(); SCH0();
    compute128(LA1, LB1, wm, wn, lr, lg, acc);
    BAR(); SCH0();
    stage128(Ag, Bg, Kk, t + 3, LA1, LB1, tid);
    VMCNT8(); BAR(); SCH0();
  }
  compute128(LA0, LB0, wm, wn, lr, lg, acc);     // tile T-2
  VMCNT0(); BAR(); SCH0();                       // tile T-1 landed
  compute128(LA1, LB1, wm, wn, lr, lg, acc);     // tile T-1

#pragma unroll
  for (int m = 0; m < 4; ++m)
#pragma unroll
    for (int n = 0; n < 4; ++n)
#pragma unroll
      for (int r = 0; r < 4; ++r) {
        const int row = m0 + wm * 64 + m * 16 + lg * 4 + r;
        const int col = n0 + wn * 64 + n * 16 + lr;
        const float val = acc[m][n][r] + bias[col]
                        + (float)resid[(size_t)row * 1024 + col];
        outf[(size_t)row * 1024 + col] = val;
      }
}

// ------------------------- flash attention (per b,h) ------------------------
// 1D grid 256, XCD-swizzled: wid = (bid&7)*32 + (bid>>3). block: 1024 = 16
// waves; wave w owns q-rows [256*(wid&7) + 16w, +16). KVBLK=128 staged ONCE
// per 256 q-rows (16 waves share). One barrier-pair per chunk; two 64-key
// halves with no barrier between. Reg-staged K/V double buffer, slot-XOR
// swizzle, swapped QK^T, log2-domain softmax with defer-max.
// Chunk loop MUST be unrolled by 2 (rule #20, round-3 lesson).
__global__ __launch_bounds__(1024) void attn_kernel(const bf16* __restrict__ q,
                                                    const bf16* __restrict__ k,
                                                    const bf16* __restrict__ vt,
                                                    bf16* __restrict__ ctxo) {
  __shared__ __align__(16) bf16 Kl[128][64];  // rows = key, 8 slots of 16B
  __shared__ __align__(16) bf16 Vt[64][128];  // rows = hd, 16 slots of 16B
  __shared__ __align__(16) bf16 Pl[16][16][64];
  const int wid = ((blockIdx.x & 7) << 5) + (blockIdx.x >> 3);
  const int bh = wid >> 3;
  const int q0 = (wid & 7) * 256;
  const int tid = threadIdx.x;
  const int lane = tid & 63, w = tid >> 6;    // w = 0..15
  const int lr = lane & 15, lg = lane >> 4;
  const int swz = lr & 7;

  const bf16* qp = q + ((size_t)bh * 2048 + q0 + w * 16) * 64;
  bf16x8 qf0 = *(const bf16x8*)&qp[lr * 64 + lg * 8];
  bf16x8 qf1 = *(const bf16x8*)&qp[lr * 64 + lg * 8 + 32];
  const float qs = 0.18033688011112042f;      // (1/8)*log2(e)
#pragma unroll
  for (int j = 0; j < 8; ++j) {
    qf0[j] = (bf16)((float)qf0[j] * qs);
    qf1[j] = (bf16)((float)qf1[j] * qs);
  }
  bf16x8 ones8;
#pragma unroll
  for (int j = 0; j < 8; ++j) ones8[j] = (bf16)1.0f;

  const bf16* kbase = k + (size_t)bh * 2048 * 64;
  const bf16* vtb = vt + (size_t)bh * 64 * 2048;

  const int skr = tid >> 3;                     // 0..127
  const int skc = (tid & 7) * 8;
  const int skcs = skc ^ ((skr & 7) << 3);
  const int svr = tid >> 4;                     // 0..63
  const int svslot = tid & 15;
  const int svs = (svslot ^ (svr & 7)) * 8;

  f32x4 acc[4] = {};
  f32x4 accl = {};
  float mq = -1e30f;

  bf16x8 kr[2], vr[2];
  kr[0] = *(const bf16x8*)&kbase[(size_t)skr * 64 + skc];
  vr[0] = *(const bf16x8*)&vtb[(size_t)svr * 2048 + svslot * 8];

#pragma unroll 2
  for (int c = 0; c < 16; ++c) {
    const int pp = c & 1;
    *(bf16x8*)&Kl[skr][skcs] = kr[pp];
    *(bf16x8*)&Vt[svr][svs]  = vr[pp];
    if (c + 1 < 16) {
      const int key0n = (c + 1) * 128;
      kr[pp ^ 1] = *(const bf16x8*)&kbase[(size_t)(key0n + skr) * 64 + skc];
      vr[pp ^ 1] = *(const bf16x8*)&vtb[(size_t)svr * 2048 + key0n + svslot * 8];
    }
    __syncthreads();

#pragma unroll
    for (int hf = 0; hf < 2; ++hf) {
      f32x4 st[4];
      __builtin_amdgcn_s_setprio(1);
#pragma unroll
      for (int ks = 0; ks < 4; ++ks) {
        const bf16x8 kf0 = *(const bf16x8*)&Kl[hf * 64 + ks * 16 + lr][(lg ^ swz) << 3];
        const bf16x8 kf1 = *(const bf16x8*)&Kl[hf * 64 + ks * 16 + lr][((lg + 4) ^ swz) << 3];
        f32x4 sa = {};
        sa = MFMA16(kf0, qf0, sa);
        sa = MFMA16(kf1, qf1, sa);
        st[ks] = sa;
      }
      __builtin_amdgcn_s_setprio(0);

      float mx = st[0][0];
#pragma unroll
      for (int ks = 0; ks < 4; ++ks)
#pragma unroll
        for (int r = 0; r < 4; ++r) mx = fmaxf(mx, st[ks][r]);
      mx = fmaxf(mx, __shfl_xor(mx, 16));
      mx = fmaxf(mx, __shfl_xor(mx, 32));
      if (!__all(mx - mq <= 8.0f)) {               // defer-max (T13)
        const float resc = exp2f(mq - mx);
        mq = mx;
        float rq[4];
#pragma unroll
        for (int r = 0; r < 4; ++r) rq[r] = __shfl(resc, lg * 4 + r);
#pragma unroll
        for (int r = 0; r < 4; ++r) {
          accl[r] *= rq[r];
#pragma unroll
          for (int jn = 0; jn < 4; ++jn) acc[jn][r] *= rq[r];
        }
      }
#pragma unroll
      for (int ks = 0; ks < 4; ++ks) {             // P pack + vectorized store
        bf16x4 pk;
#pragma unroll
        for (int r = 0; r < 4; ++r) pk[r] = (bf16)exp2f(st[ks][r] - mq);
        const int col = (((ks * 2 + (lg >> 1)) ^ swz) << 3) + ((lg & 1) << 2);
        *(bf16x4*)&Pl[w][lr][col] = pk;
      }

      const bf16x8 pf0 = *(const bf16x8*)&Pl[w][lr][(lg ^ swz) << 3];
      const bf16x8 pf1 = *(const bf16x8*)&Pl[w][lr][((lg + 4) ^ swz) << 3];
      __builtin_amdgcn_s_setprio(1);
#pragma unroll
      for (int jn = 0; jn < 4; ++jn) {
        const bf16x8 vf0 = *(const bf16x8*)&Vt[jn * 16 + lr][hf * 64 + ((lg ^ swz) << 3)];
        const bf16x8 vf1 = *(const bf16x8*)&Vt[jn * 16 + lr][hf * 64 + (((lg + 4) ^ swz) << 3)];
        acc[jn] = MFMA16(pf0, vf0, acc[jn]);
        acc[jn] = MFMA16(pf1, vf1, acc[jn]);
      }
      accl = MFMA16(pf0, ones8, accl);
      accl = MFMA16(pf1, ones8, accl);
      __builtin_amdgcn_s_setprio(0);
    }
    __syncthreads();
  }

  const int bb = bh >> 4, hh = bh & 15;
#pragma unroll
  for (int r = 0; r < 4; ++r) {
    const float inv = 1.f / accl[r];
    const size_t rowg = (size_t)bb * 2048 + q0 + w * 16 + lg * 4 + r;
#pragma unroll
    for (int jn = 0; jn < 4; ++jn)
      ctxo[rowg * 1024 + hh * 64 + jn * 16 + lr] = (bf16)(acc[jn][r] * inv);
  }
}

// ---------- fused split-K reduce + bias + residual + LayerNorm --------------
template <int NP>
__global__ __launch_bounds__(256) void ln2_kernel(const float* __restrict__ p,
                                                  const bf16* __restrict__ resid,
                                                  const float* __restrict__ bias,
                                                  const float* __restrict__ g,
                                                  const float* __restrict__ be,
                                                  bf16* __restrict__ xo,
                                                  float* __restrict__ fout) {
  const int row = blockIdx.x, tid = threadIdx.x;
  const bf16x4 rv = *(const bf16x4*)&resid[(size_t)row * 1024 + tid * 4];
  const float4 bb = ((const float4*)bias)[tid];
  float4 v;
  v.x = bb.x + (float)rv[0];
  v.y = bb.y + (float)rv[1];
  v.z = bb.z + (float)rv[2];
  v.w = bb.w + (float)rv[3];
#pragma unroll
  for (int pl = 0; pl < NP; ++pl) {
    const float4 a = ((const float4*)(p + (size_t)pl * 4096 * 1024 + (size_t)row * 1024))[tid];
    v.x += a.x; v.y += a.y; v.z += a.z; v.w += a.w;
  }
  float s = v.x + v.y + v.z + v.w;
  float s2 = v.x * v.x + v.y * v.y + v.z * v.z + v.w * v.w;
#pragma unroll
  for (int o = 32; o > 0; o >>= 1) { s += __shfl_down(s, o); s2 += __shfl_down(s2, o); }
  __shared__ float red[8];
  if ((tid & 63) == 0) { red[tid >> 6] = s; red[4 + (tid >> 6)] = s2; }
  __syncthreads();
  s = red[0] + red[1] + red[2] + red[3];
  s2 = red[4] + red[5] + red[6] + red[7];
  const float mean = s * (1.f / 1024.f);
  const float var = s2 * (1.f / 1024.f) - mean * mean;
  const float rstd = rsqrtf(var + 1e-5f);
  const float4 gv = ((const float4*)g)[tid];
  const float4 bv = ((const float4*)be)[tid];
  float4 of;
  of.x = (v.x - mean) * rstd * gv.x + bv.x;
  of.y = (v.y - mean) * rstd * gv.y + bv.y;
  of.z = (v.z - mean) * rstd * gv.z + bv.z;
  of.w = (v.w - mean) * rstd * gv.w + bv.w;
  if (fout) {
    ((float4*)(fout + (size_t)row * 1024))[tid] = of;
  } else {
    bf16x4 o4;
    o4[0] = (bf16)of.x; o4[1] = (bf16)of.y; o4[2] = (bf16)of.z; o4[3] = (bf16)of.w;
    *(bf16x4*)&xo[(size_t)row * 1024 + tid * 4] = o4;
  }
}

// ------------------------------ LayerNorm (fp32 y) --------------------------
__global__ __launch_bounds__(256) void ln_kernel(const float* __restrict__ y,
                                                 const float* __restrict__ g,
                                                 const float* __restrict__ be,
                                                 bf16* __restrict__ xo) {
  const int row = blockIdx.x, tid = threadIdx.x;
  const float4 v = ((const float4*)(y + (size_t)row * 1024))[tid];
  float s = v.x + v.y + v.z + v.w;
  float s2 = v.x * v.x + v.y * v.y + v.z * v.z + v.w * v.w;
#pragma unroll
  for (int o = 32; o > 0; o >>= 1) { s += __shfl_down(s, o); s2 += __shfl_down(s2, o); }
  __shared__ float red[8];
  if ((tid & 63) == 0) { red[tid >> 6] = s; red[4 + (tid >> 6)] = s2; }
  __syncthreads();
  s = red[0] + red[1] + red[2] + red[3];
  s2 = red[4] + red[5] + red[6] + red[7];
  const float mean = s * (1.f / 1024.f);
  const float var = s2 * (1.f / 1024.f) - mean * mean;
  const float rstd = rsqrtf(var + 1e-5f);
  const float4 gv = ((const float4*)g)[tid];
  const float4 bv = ((const float4*)be)[tid];
  bf16x4 o4;
  o4[0] = (bf16)((v.x - mean) * rstd * gv.x + bv.x);
  o4[1] = (bf16)((v.y - mean) * rstd * gv.y + bv.y);
  o4[2] = (bf16)((v.z - mean) * rstd * gv.z + bv.z);
  o4[3] = (bf16)((v.w - mean) * rstd * gv.w + bv.w);
  *(bf16x4*)&xo[(size_t)row * 1024 + tid * 4] = o4;
}

// ----------------------------------------------------------------------------
extern "C" void kernel_launch(void* const* d_in, const int* in_sizes, int n_in,
                              void* d_out, int out_size, void* d_ws, size_t ws_size,
                              hipStream_t stream) {
  const int* tokens = (const int*)d_in[0];
  const float* emb = (const float*)d_in[2];
  const float* Wq = (const float*)d_in[3];
  const float* bq = (const float*)d_in[4];
  const float* Wk = (const float*)d_in[5];
  const float* bk = (const float*)d_in[6];
  const float* Wv = (const float*)d_in[7];
  const float* bv = (const float*)d_in[8];
  const float* Wo = (const float*)d_in[9];
  const float* bo = (const float*)d_in[10];
  const float* W1 = (const float*)d_in[11];
  const float* b1 = (const float*)d_in[12];
  const float* W2 = (const float*)d_in[13];
  const float* b2 = (const float*)d_in[14];
  const float* g1 = (const float*)d_in[15];
  const float* be1 = (const float*)d_in[16];
  const float* g2 = (const float*)d_in[17];
  const float* be2 = (const float*)d_in[18];

  char* p = (char*)d_ws;
  auto carve = [&](size_t bytes) { char* r = p; p += (bytes + 255) & ~(size_t)255; return r; };

  const size_t QKV_E = (size_t)3072 * 1024;   // elems per layer
  const size_t O_E   = (size_t)1024 * 1024;
  const size_t W1_E  = (size_t)4096 * 1024;
  const size_t W2_E  = (size_t)1024 * 4096;
  const size_t restBytes =
      5 * ((size_t)4096 * 1024 * 2)           // xb,qb,kb,vtb,ctxb
      + (size_t)4096 * 1024 * 4               // yb
      + (size_t)4 * 4096 * 1024 * 4           // pb
      + (size_t)4096 * 4096 * 2               // hb
      + 16 * 256;                             // padding slop
  const size_t wt6Bytes = 6 * (QKV_E + O_E + W1_E + W2_E) * 2;
  const size_t wt1Bytes = (QKV_E + O_E + W1_E + W2_E) * 2;
  const bool hoist = ws_size >= wt6Bytes + restBytes + 4096;
  const int nl = hoist ? 6 : 1;

  bf16* wt_qkv = (bf16*)carve(nl * QKV_E * 2);
  bf16* wt_o   = (bf16*)carve(nl * O_E * 2);
  bf16* wt_1   = (bf16*)carve(nl * W1_E * 2);
  bf16* wt_2   = (bf16*)carve(nl * W2_E * 2);
  bf16* xb     = (bf16*)carve((size_t)4096 * 1024 * 2);
  bf16* qb     = (bf16*)carve((size_t)4096 * 1024 * 2);
  bf16* kb     = (bf16*)carve((size_t)4096 * 1024 * 2);
  bf16* vtb    = (bf16*)carve((size_t)4096 * 1024 * 2);
  bf16* ctxb   = (bf16*)carve((size_t)4096 * 1024 * 2);
  float* yb    = (float*)carve((size_t)4096 * 1024 * 4);
  float* pb    = (float*)carve((size_t)4 * 4096 * 1024 * 4);   // split-K partials
  bf16* hb     = (bf16*)carve((size_t)4096 * 4096 * 2);
  (void)wt1Bytes;

  if (hoist) {
    // all 6 layers' weight transposes in ONE dispatch
    wtrans_all<<<6 * 3072, 256, 0, stream>>>(Wq, Wk, Wv, Wo, W1, W2,
        wt_qkv, wt_o, wt_1, wt_2,
        (long)QKV_E, (long)O_E, (long)W1_E, (long)W2_E);
  }

  embed_kernel<<<4096, 256, 0, stream>>>(tokens, emb, xb);

  for (int l = 0; l < 6; ++l) {
    bf16* wqkv_l = wt_qkv + (hoist ? (size_t)l * QKV_E : 0);
    bf16* wo_l   = wt_o   + (hoist ? (size_t)l * O_E   : 0);
    bf16* w1_l   = wt_1   + (hoist ? (size_t)l * W1_E  : 0);
    bf16* w2_l   = wt_2   + (hoist ? (size_t)l * W2_E  : 0);

    if (!hoist) {
      wtrans_all<<<3072, 256, 0, stream>>>(
          Wq + (size_t)l * 1024 * 1024, Wk + (size_t)l * 1024 * 1024,
          Wv + (size_t)l * 1024 * 1024, Wo + (size_t)l * 1024 * 1024,
          W1 + (size_t)l * 1024 * 4096, W2 + (size_t)l * 4096 * 1024,
          wqkv_l, wo_l, w1_l, w2_l, 0, 0, 0, 0);
    }

    // QKV: 256x192 tile, nbx = 16 -> grid 256 = 1 block/CU. V written
    // directly transposed into vtb (vtrans fused).
    gemm256<0, 3><<<256, 512, 0, stream>>>(xb, wqkv_l, 1024, 1024, 3072, 16,
        bq + (size_t)l * 1024, bk + (size_t)l * 1024, bv + (size_t)l * 1024,
        nullptr, nullptr, qb, kb, vtb);

    // attn: 16-wave blocks, Q=256, grid 256
    attn_kernel<<<256, 1024, 0, stream>>>(qb, kb, vtb, ctxb);

    // O-proj: 128^2 pipeline, single-pass K=1024, grid 256
    gemm128p<<<256, 256, 0, stream>>>(ctxb, wo_l, 1024,
        bo + (size_t)l * 1024, xb, yb);
    ln_kernel<<<4096, 256, 0, stream>>>(yb, g1 + (size_t)l * 1024,
        be1 + (size_t)l * 1024, xb);

    // FFN1: 256^2 tile, grid 16x16 = 256
    gemm256<2, 4><<<256, 512, 0, stream>>>(xb, w1_l, 1024, 1024, 4096, 16,
        b1 + (size_t)l * 4096, nullptr, nullptr, hb,
        nullptr, nullptr, nullptr, nullptr);

    // FFN2: 256^2 tile split-K=4 (K-slice 1024), grid (64,4) = 256 blocks
    gemm256<1, 4><<<dim3(64, 4), 512, 0, stream>>>(hb, w2_l, 4096, 1024, 1024, 4,
        nullptr, nullptr, nullptr, nullptr, pb,
        nullptr, nullptr, nullptr);
    ln2_kernel<4><<<4096, 256, 0, stream>>>(pb, xb, b2 + (size_t)l * 1024,
        g2 + (size_t)l * 1024, be2 + (size_t)l * 1024, xb,
        (l == 5) ? (float*)d_out : nullptr);
  }
}

// Round 18
// 1355.640 us; speedup vs baseline: 1.0293x; 1.0293x over previous
//
#include <hip/hip_runtime.h>
#include <hip/hip_bf16.h>
#include <cstdint>
#include <cstddef>

// ---------------------------------------------------------------------------
// Transformer encoder, 6 layers: B=2,S=2048,D=1024,H=16,HD=64,F=4096.
// QKV: 256x192-tile (grid 256 = 1/CU), V written directly transposed.
// FFN1: 256^2. Both: 8-wave counted-vmcnt double buffer (T2+T3+T4+T5).
// FFN2: gemm256 split-K=4 + fused LN. O-proj: 128^2 pipeline.
// Flash attention: 16-wave blocks (Q=256), KVBLK=128, XCD-swizzled grid,
// swapped QK^T, T2 swizzle, reg-staged K/V double buffer.
// (r17 wtrans-hoist reverted: fused 6-layer transpose ran at 2.5 TB/s vs
//  6 TB/s per-layer -- L2/L3 locality loss at 432 MB working set.)
// ---------------------------------------------------------------------------

typedef __bf16 bf16;
typedef __bf16 bf16x2 __attribute__((ext_vector_type(2)));
typedef __bf16 bf16x4 __attribute__((ext_vector_type(4)));
typedef __bf16 bf16x8 __attribute__((ext_vector_type(8)));
typedef float  f32x4  __attribute__((ext_vector_type(4)));

#define MFMA16(a, b, c) __builtin_amdgcn_mfma_f32_16x16x32_bf16((a), (b), (c), 0, 0, 0)

static __device__ __forceinline__ void load_lds16(const void* g, void* l) {
  __builtin_amdgcn_global_load_lds((const __attribute__((address_space(1))) void*)g,
                                   (__attribute__((address_space(3))) void*)l, 16, 0, 0);
}

#define BAR()   __builtin_amdgcn_s_barrier()
#define SCH0()  __builtin_amdgcn_sched_barrier(0)
#define VMCNT8() asm volatile("s_waitcnt vmcnt(8)" ::: "memory")
#define VMCNT7() asm volatile("s_waitcnt vmcnt(7)" ::: "memory")
#define VMCNT0() asm volatile("s_waitcnt vmcnt(0)" ::: "memory")

// ---------------- embedding + positional encoding -> bf16 x ----------------
__global__ __launch_bounds__(256) void embed_kernel(const int* __restrict__ tok,
                                                    const float* __restrict__ emb,
                                                    bf16* __restrict__ xo) {
  const int row = blockIdx.x;          // b*2048 + s
  const int s = row & 2047;
  const int t = tok[row];
  const int d0 = threadIdx.x * 4;
  const float4 e = *(const float4*)&emb[(size_t)t * 1024 + d0];
  const float* ef = (const float*)&e;
  bf16x4 o4;
#pragma unroll
  for (int j = 0; j < 4; ++j) {
    const int d = d0 + j;
    const float div = __expf(-(float)(d & ~1) * 0.00899447301950864f); // ln(1e4)/1024
    const float arg = (float)s * div;
    const float pe = (d & 1) ? cosf(arg) : sinf(arg);
    o4[j] = (bf16)(ef[j] + pe);
  }
  *(bf16x4*)&xo[(size_t)row * 1024 + d0] = o4;
}

// ------------- weight transpose: fp32 [K][N] -> bf16 [N][K], batched --------
struct TJob { const float* src; bf16* dst; int K; int N; int t0; };
struct TArgs { TJob j[6]; };

__global__ __launch_bounds__(256) void wtrans_kernel(TArgs a) {
  __shared__ float t[64][65];
  const int blk = blockIdx.x;
  const float* src = a.j[0].src; bf16* dst = a.j[0].dst;
  int K = a.j[0].K, N = a.j[0].N, t0 = a.j[0].t0;
#pragma unroll
  for (int q = 1; q < 6; ++q)
    if (blk >= a.j[q].t0) { src = a.j[q].src; dst = a.j[q].dst; K = a.j[q].K; N = a.j[q].N; t0 = a.j[q].t0; }
  const int tj = blk - t0;
  const int tilesK = K >> 6;
  const int tk = (tj % tilesK) << 6;
  const int tn = (tj / tilesK) << 6;
  const int tid = threadIdx.x;
  const int rr = tid >> 4;            // 0..15
  const int c4 = (tid & 15) * 4;
#pragma unroll
  for (int i = 0; i < 4; ++i) {
    const float4 v = *(const float4*)&src[(size_t)(tk + rr + 16 * i) * N + tn + c4];
    t[rr + 16 * i][c4 + 0] = v.x;
    t[rr + 16 * i][c4 + 1] = v.y;
    t[rr + 16 * i][c4 + 2] = v.z;
    t[rr + 16 * i][c4 + 3] = v.w;
  }
  __syncthreads();
  const int k0 = (tid & 15) * 4;
#pragma unroll
  for (int i = 0; i < 4; ++i) {
    const int n = rr + 16 * i;
    bf16x4 o;
#pragma unroll
    for (int j = 0; j < 4; ++j) o[j] = (bf16)t[k0 + j][n];
    *(bf16x4*)&dst[(size_t)(tn + n) * K + tk + k0] = o;
  }
}

// ======================= shared GEMM building blocks ========================
static __device__ __forceinline__ bf16x8 ldsfrag(const bf16* base, int row, int colb) {
  int off = row * 128 + colb;
  off ^= ((off >> 7) & 7) << 4;
  return *(const bf16x8*)((const char*)base + off);
}

// ====== 256xBN-tile 8-wave GEMM, counted-vmcnt (BN = 64*BNF, BNF=3|4) ======
template <int BNF>
static __device__ __forceinline__ void stage_tileT(const bf16* __restrict__ Ag,
    const bf16* __restrict__ Bg, int Kstr, int kt, bf16* lA, bf16* lB, int tid) {
  const char* wbaseA = (const char*)lA + ((tid >> 6) << 10);
  const char* wbaseB = (const char*)lB + ((tid >> 6) << 10);
#pragma unroll
  for (int s = 0; s < 4; ++s) {
    const int L = s * 8192 + tid * 16;
    const int off = L ^ (((L >> 7) & 7) << 4);
    load_lds16(Ag + (size_t)(off >> 7) * Kstr + kt * 64 + ((off & 127) >> 1),
               (void*)(wbaseA + s * 8192));
  }
#pragma unroll
  for (int s = 0; s < BNF; ++s) {
    const int L = s * 8192 + tid * 16;
    const int off = L ^ (((L >> 7) & 7) << 4);
    load_lds16(Bg + (size_t)(off >> 7) * Kstr + kt * 64 + ((off & 127) >> 1),
               (void*)(wbaseB + s * 8192));
  }
}

template <int BNF>
static __device__ __forceinline__ void compute_tileT(const bf16* lA, const bf16* lB,
    int wm, int wn, int lr, int lg, f32x4 (&acc)[8][BNF]) {
  bf16x8 bfr[BNF][2];
#pragma unroll
  for (int n = 0; n < BNF; ++n)
#pragma unroll
    for (int kk = 0; kk < 2; ++kk)
      bfr[n][kk] = ldsfrag(lB, wn * (16 * BNF) + n * 16 + lr, kk * 64 + lg * 16);
#pragma unroll
  for (int m = 0; m < 8; ++m) {
    const bf16x8 a0 = ldsfrag(lA, wm * 128 + m * 16 + lr, lg * 16);
    const bf16x8 a1 = ldsfrag(lA, wm * 128 + m * 16 + lr, 64 + lg * 16);
    __builtin_amdgcn_s_setprio(1);
#pragma unroll
    for (int n = 0; n < BNF; ++n) {
      acc[m][n] = MFMA16(a0, bfr[n][0], acc[m][n]);
      acc[m][n] = MFMA16(a1, bfr[n][1], acc[m][n]);
    }
    __builtin_amdgcn_s_setprio(0);
  }
}

template <int BNF>
static __device__ __forceinline__ void waitK() {
  if constexpr (BNF == 3) { VMCNT7(); } else { VMCNT8(); }
}

template <int EPI, int BNF>  // EPI 0: qkv scatter (V transposed), 1: fp32 partial, 2: bias+relu
__global__ __launch_bounds__(512, 2) void gemm256(
    const bf16* __restrict__ A, const bf16* __restrict__ Bt,
    int Kstr, int Kloop, int Nn, int nbx,
    const float* __restrict__ bias0, const float* __restrict__ bias1,
    const float* __restrict__ bias2, bf16* __restrict__ outb,
    float* __restrict__ pout,
    bf16* __restrict__ q_out, bf16* __restrict__ k_out, bf16* __restrict__ vt_out) {
  __shared__ __align__(16) bf16 ldsA[2][16384];       // 32KB each
  __shared__ __align__(16) bf16 ldsB[2][BNF * 4096];  // BNF*8KB each
  const int bz = blockIdx.y;
  const bf16* Abase = A + (size_t)bz * Kloop;
  const bf16* Bbase = Bt + (size_t)bz * Kloop;
  const int cpx = gridDim.x >> 3;
  const int wg = (blockIdx.x & 7) * cpx + (blockIdx.x >> 3);
  const int bx = wg % nbx, by = wg / nbx;
  const int tid = threadIdx.x;
  const int lane = tid & 63, wave = tid >> 6;
  const int lr = lane & 15, lg = lane >> 4;
  const int wm = wave >> 2, wn = wave & 3;
  const int m0 = by * 256, n0 = bx * (64 * BNF);

  const bf16* Ag = Abase + (size_t)m0 * Kstr;
  const bf16* Bg = Bbase + (size_t)n0 * Kstr;

  f32x4 acc[8][BNF] = {};
  const int T = Kloop >> 6;

  stage_tileT<BNF>(Ag, Bg, Kstr, 0, ldsA[0], ldsB[0], tid);
  stage_tileT<BNF>(Ag, Bg, Kstr, 1, ldsA[1], ldsB[1], tid);
  waitK<BNF>(); BAR(); SCH0();

  for (int t = 0; t + 3 < T; t += 2) {
    compute_tileT<BNF>(ldsA[0], ldsB[0], wm, wn, lr, lg, acc);
    BAR(); SCH0();
    stage_tileT<BNF>(Ag, Bg, Kstr, t + 2, ldsA[0], ldsB[0], tid);
    waitK<BNF>(); BAR(); SCH0();
    compute_tileT<BNF>(ldsA[1], ldsB[1], wm, wn, lr, lg, acc);
    BAR(); SCH0();
    stage_tileT<BNF>(Ag, Bg, Kstr, t + 3, ldsA[1], ldsB[1], tid);
    waitK<BNF>(); BAR(); SCH0();
  }
  compute_tileT<BNF>(ldsA[0], ldsB[0], wm, wn, lr, lg, acc);  // tile T-2
  VMCNT0(); BAR(); SCH0();                                    // tile T-1 landed
  compute_tileT<BNF>(ldsA[1], ldsB[1], wm, wn, lr, lg, acc);  // tile T-1

#pragma unroll
  for (int m = 0; m < 8; ++m)
#pragma unroll
    for (int n = 0; n < BNF; ++n) {
      if (EPI == 0) {
        // col range of this fragment is 16-aligned -> segment-uniform
        const int col = n0 + wn * (16 * BNF) + n * 16 + lr;
        const int which = col >> 10, hc = col & 1023;
        const int h = hc >> 6, hd = hc & 63;
        const int row0 = m0 + wm * 128 + m * 16 + lg * 4;
        const int b = row0 >> 11, s0 = row0 & 2047;
        if (which == 2) {
          // V: 4 consecutive s at fixed hd -> one bf16x4 in [bh][hd][s] layout
          bf16x4 o;
#pragma unroll
          for (int r = 0; r < 4; ++r) o[r] = (bf16)(acc[m][n][r] + bias2[hc]);
          *(bf16x4*)&vt_out[(((size_t)b * 16 + h) * 64 + hd) * 2048 + s0] = o;
        } else {
          const float* bs = (which == 0) ? bias0 : bias1;
          bf16* dst = (which == 0) ? q_out : k_out;
#pragma unroll
          for (int r = 0; r < 4; ++r)
            dst[(((size_t)b * 16 + h) * 2048 + s0 + r) * 64 + hd] =
                (bf16)(acc[m][n][r] + bs[hc]);
        }
      } else {
#pragma unroll
        for (int r = 0; r < 4; ++r) {
          const int row = m0 + wm * 128 + m * 16 + lg * 4 + r;
          const int col = n0 + wn * (16 * BNF) + n * 16 + lr;
          float val = acc[m][n][r];
          if (EPI == 1) {
            pout[(size_t)bz * 4096 * 1024 + (size_t)row * 1024 + col] = val;
          } else {
            val += bias0[col];
            outb[(size_t)row * Nn + col] = (bf16)(val > 0.f ? val : 0.f);
          }
        }
      }
    }
}

// ========== 128x128-tile 4-wave GEMM, counted-vmcnt (O-proj K=1024) =========
static __device__ __forceinline__ void stage128(const bf16* __restrict__ Ag,
    const bf16* __restrict__ Bg, int Kstr, int kt, bf16* lA, bf16* lB, int tid) {
  const char* dA = (const char*)lA + ((tid >> 6) << 10);
  const char* dB = (const char*)lB + ((tid >> 6) << 10);
#pragma unroll
  for (int s = 0; s < 4; ++s) {
    const int L = s * 4096 + tid * 16;
    const int off = L ^ (((L >> 7) & 7) << 4);
    load_lds16(Ag + (size_t)(off >> 7) * Kstr + kt * 64 + ((off & 127) >> 1),
               (void*)(dA + s * 4096));
  }
#pragma unroll
  for (int s = 0; s < 4; ++s) {
    const int L = s * 4096 + tid * 16;
    const int off = L ^ (((L >> 7) & 7) << 4);
    load_lds16(Bg + (size_t)(off >> 7) * Kstr + kt * 64 + ((off & 127) >> 1),
               (void*)(dB + s * 4096));
  }
}

static __device__ __forceinline__ void compute128(const bf16* lA, const bf16* lB,
    int wm, int wn, int lr, int lg, f32x4 (&acc)[4][4]) {
  bf16x8 bfr[4][2];
#pragma unroll
  for (int n = 0; n < 4; ++n)
#pragma unroll
    for (int kk = 0; kk < 2; ++kk)
      bfr[n][kk] = ldsfrag(lB, wn * 64 + n * 16 + lr, kk * 64 + lg * 16);
#pragma unroll
  for (int m = 0; m < 4; ++m) {
    const bf16x8 a0 = ldsfrag(lA, wm * 64 + m * 16 + lr, lg * 16);
    const bf16x8 a1 = ldsfrag(lA, wm * 64 + m * 16 + lr, 64 + lg * 16);
    __builtin_amdgcn_s_setprio(1);
#pragma unroll
    for (int n = 0; n < 4; ++n) {
      acc[m][n] = MFMA16(a0, bfr[n][0], acc[m][n]);
      acc[m][n] = MFMA16(a1, bfr[n][1], acc[m][n]);
    }
    __builtin_amdgcn_s_setprio(0);
  }
}

__global__ __launch_bounds__(256, 2) void gemm128p(
    const bf16* __restrict__ A, const bf16* __restrict__ Bt, int Kk,
    const float* __restrict__ bias, const bf16* __restrict__ resid,
    float* __restrict__ outf) {
  __shared__ __align__(16) bf16 lds[4][8192];    // A0,B0,A1,B1 (16KB each)
  const int cpx = gridDim.x >> 3;
  const int wg = (blockIdx.x & 7) * cpx + (blockIdx.x >> 3);
  const int bx = wg & 7, by = wg >> 3;           // nbx = 8 (N=1024)
  const int tid = threadIdx.x;
  const int lane = tid & 63, wave = tid >> 6;
  const int lr = lane & 15, lg = lane >> 4;
  const int wm = wave >> 1, wn = wave & 1;
  const int m0 = by * 128, n0 = bx * 128;

  const bf16* Ag = A + (size_t)m0 * Kk;
  const bf16* Bg = Bt + (size_t)n0 * Kk;
  bf16* LA0 = lds[0]; bf16* LB0 = lds[1];
  bf16* LA1 = lds[2]; bf16* LB1 = lds[3];

  f32x4 acc[4][4] = {};
  const int T = Kk >> 6;

  stage128(Ag, Bg, Kk, 0, LA0, LB0, tid);
  stage128(Ag, Bg, Kk, 1, LA1, LB1, tid);
  VMCNT8(); BAR(); SCH0();

  for (int t = 0; t + 3 < T; t += 2) {
    compute128(LA0, LB0, wm, wn, lr, lg, acc);
    BAR(); SCH0();
    stage128(Ag, Bg, Kk, t + 2, LA0, LB0, tid);
    VMCNT8(); BAR(); SCH0();
    compute128(LA1, LB1, wm, wn, lr, lg, acc);
    BAR(); SCH0();
    stage128(Ag, Bg, Kk, t + 3, LA1, LB1, tid);
    VMCNT8(); BAR(); SCH0();
  }
  compute128(LA0, LB0, wm, wn, lr, lg, acc);     // tile T-2
  VMCNT0(); BAR(); SCH0();                       // tile T-1 landed
  compute128(LA1, LB1, wm, wn, lr, lg, acc);     // tile T-1

#pragma unroll
  for (int m = 0; m < 4; ++m)
#pragma unroll
    for (int n = 0; n < 4; ++n)
#pragma unroll
      for (int r = 0; r < 4; ++r) {
        const int row = m0 + wm * 64 + m * 16 + lg * 4 + r;
        const int col = n0 + wn * 64 + n * 16 + lr;
        const float val = acc[m][n][r] + bias[col]
                        + (float)resid[(size_t)row * 1024 + col];
        outf[(size_t)row * 1024 + col] = val;
      }
}

// ------------------------- flash attention (per b,h) ------------------------
// 1D grid 256, XCD-swizzled: wid = (bid&7)*32 + (bid>>3). block: 1024 = 16
// waves; wave w owns q-rows [256*(wid&7) + 16w, +16). KVBLK=128 staged ONCE
// per 256 q-rows (16 waves share). One barrier-pair per chunk; two 64-key
// halves with no barrier between. Reg-staged K/V double buffer, slot-XOR
// swizzle, swapped QK^T, log2-domain softmax with defer-max.
// Chunk loop MUST be unrolled by 2 (rule #20, round-3 lesson).
__global__ __launch_bounds__(1024) void attn_kernel(const bf16* __restrict__ q,
                                                    const bf16* __restrict__ k,
                                                    const bf16* __restrict__ vt,
                                                    bf16* __restrict__ ctxo) {
  __shared__ __align__(16) bf16 Kl[128][64];  // rows = key, 8 slots of 16B
  __shared__ __align__(16) bf16 Vt[64][128];  // rows = hd, 16 slots of 16B
  __shared__ __align__(16) bf16 Pl[16][16][64];
  const int wid = ((blockIdx.x & 7) << 5) + (blockIdx.x >> 3);
  const int bh = wid >> 3;
  const int q0 = (wid & 7) * 256;
  const int tid = threadIdx.x;
  const int lane = tid & 63, w = tid >> 6;    // w = 0..15
  const int lr = lane & 15, lg = lane >> 4;
  const int swz = lr & 7;

  const bf16* qp = q + ((size_t)bh * 2048 + q0 + w * 16) * 64;
  bf16x8 qf0 = *(const bf16x8*)&qp[lr * 64 + lg * 8];
  bf16x8 qf1 = *(const bf16x8*)&qp[lr * 64 + lg * 8 + 32];
  const float qs = 0.18033688011112042f;      // (1/8)*log2(e)
#pragma unroll
  for (int j = 0; j < 8; ++j) {
    qf0[j] = (bf16)((float)qf0[j] * qs);
    qf1[j] = (bf16)((float)qf1[j] * qs);
  }
  bf16x8 ones8;
#pragma unroll
  for (int j = 0; j < 8; ++j) ones8[j] = (bf16)1.0f;

  const bf16* kbase = k + (size_t)bh * 2048 * 64;
  const bf16* vtb = vt + (size_t)bh * 64 * 2048;

  const int skr = tid >> 3;                     // 0..127
  const int skc = (tid & 7) * 8;
  const int skcs = skc ^ ((skr & 7) << 3);
  const int svr = tid >> 4;                     // 0..63
  const int svslot = tid & 15;
  const int svs = (svslot ^ (svr & 7)) * 8;

  f32x4 acc[4] = {};
  f32x4 accl = {};
  float mq = -1e30f;

  bf16x8 kr[2], vr[2];
  kr[0] = *(const bf16x8*)&kbase[(size_t)skr * 64 + skc];
  vr[0] = *(const bf16x8*)&vtb[(size_t)svr * 2048 + svslot * 8];

#pragma unroll 2
  for (int c = 0; c < 16; ++c) {
    const int pp = c & 1;
    *(bf16x8*)&Kl[skr][skcs] = kr[pp];
    *(bf16x8*)&Vt[svr][svs]  = vr[pp];
    if (c + 1 < 16) {
      const int key0n = (c + 1) * 128;
      kr[pp ^ 1] = *(const bf16x8*)&kbase[(size_t)(key0n + skr) * 64 + skc];
      vr[pp ^ 1] = *(const bf16x8*)&vtb[(size_t)svr * 2048 + key0n + svslot * 8];
    }
    __syncthreads();

#pragma unroll
    for (int hf = 0; hf < 2; ++hf) {
      f32x4 st[4];
      __builtin_amdgcn_s_setprio(1);
#pragma unroll
      for (int ks = 0; ks < 4; ++ks) {
        const bf16x8 kf0 = *(const bf16x8*)&Kl[hf * 64 + ks * 16 + lr][(lg ^ swz) << 3];
        const bf16x8 kf1 = *(const bf16x8*)&Kl[hf * 64 + ks * 16 + lr][((lg + 4) ^ swz) << 3];
        f32x4 sa = {};
        sa = MFMA16(kf0, qf0, sa);
        sa = MFMA16(kf1, qf1, sa);
        st[ks] = sa;
      }
      __builtin_amdgcn_s_setprio(0);

      float mx = st[0][0];
#pragma unroll
      for (int ks = 0; ks < 4; ++ks)
#pragma unroll
        for (int r = 0; r < 4; ++r) mx = fmaxf(mx, st[ks][r]);
      mx = fmaxf(mx, __shfl_xor(mx, 16));
      mx = fmaxf(mx, __shfl_xor(mx, 32));
      if (!__all(mx - mq <= 8.0f)) {               // defer-max (T13)
        const float resc = exp2f(mq - mx);
        mq = mx;
        float rq[4];
#pragma unroll
        for (int r = 0; r < 4; ++r) rq[r] = __shfl(resc, lg * 4 + r);
#pragma unroll
        for (int r = 0; r < 4; ++r) {
          accl[r] *= rq[r];
#pragma unroll
          for (int jn = 0; jn < 4; ++jn) acc[jn][r] *= rq[r];
        }
      }
#pragma unroll
      for (int ks = 0; ks < 4; ++ks) {             // P pack + vectorized store
        bf16x4 pk;
#pragma unroll
        for (int r = 0; r < 4; ++r) pk[r] = (bf16)exp2f(st[ks][r] - mq);
        const int col = (((ks * 2 + (lg >> 1)) ^ swz) << 3) + ((lg & 1) << 2);
        *(bf16x4*)&Pl[w][lr][col] = pk;
      }

      const bf16x8 pf0 = *(const bf16x8*)&Pl[w][lr][(lg ^ swz) << 3];
      const bf16x8 pf1 = *(const bf16x8*)&Pl[w][lr][((lg + 4) ^ swz) << 3];
      __builtin_amdgcn_s_setprio(1);
#pragma unroll
      for (int jn = 0; jn < 4; ++jn) {
        const bf16x8 vf0 = *(const bf16x8*)&Vt[jn * 16 + lr][hf * 64 + ((lg ^ swz) << 3)];
        const bf16x8 vf1 = *(const bf16x8*)&Vt[jn * 16 + lr][hf * 64 + (((lg + 4) ^ swz) << 3)];
        acc[jn] = MFMA16(pf0, vf0, acc[jn]);
        acc[jn] = MFMA16(pf1, vf1, acc[jn]);
      }
      accl = MFMA16(pf0, ones8, accl);
      accl = MFMA16(pf1, ones8, accl);
      __builtin_amdgcn_s_setprio(0);
    }
    __syncthreads();
  }

  const int bb = bh >> 4, hh = bh & 15;
#pragma unroll
  for (int r = 0; r < 4; ++r) {
    const float inv = 1.f / accl[r];
    const size_t rowg = (size_t)bb * 2048 + q0 + w * 16 + lg * 4 + r;
#pragma unroll
    for (int jn = 0; jn < 4; ++jn)
      ctxo[rowg * 1024 + hh * 64 + jn * 16 + lr] = (bf16)(acc[jn][r] * inv);
  }
}

// ---------- fused split-K reduce + bias + residual + LayerNorm --------------
template <int NP>
__global__ __launch_bounds__(256) void ln2_kernel(const float* __restrict__ p,
                                                  const bf16* __restrict__ resid,
                                                  const float* __restrict__ bias,
                                                  const float* __restrict__ g,
                                                  const float* __restrict__ be,
                                                  bf16* __restrict__ xo,
                                                  float* __restrict__ fout) {
  const int row = blockIdx.x, tid = threadIdx.x;
  const bf16x4 rv = *(const bf16x4*)&resid[(size_t)row * 1024 + tid * 4];
  const float4 bb = ((const float4*)bias)[tid];
  float4 v;
  v.x = bb.x + (float)rv[0];
  v.y = bb.y + (float)rv[1];
  v.z = bb.z + (float)rv[2];
  v.w = bb.w + (float)rv[3];
#pragma unroll
  for (int pl = 0; pl < NP; ++pl) {
    const float4 a = ((const float4*)(p + (size_t)pl * 4096 * 1024 + (size_t)row * 1024))[tid];
    v.x += a.x; v.y += a.y; v.z += a.z; v.w += a.w;
  }
  float s = v.x + v.y + v.z + v.w;
  float s2 = v.x * v.x + v.y * v.y + v.z * v.z + v.w * v.w;
#pragma unroll
  for (int o = 32; o > 0; o >>= 1) { s += __shfl_down(s, o); s2 += __shfl_down(s2, o); }
  __shared__ float red[8];
  if ((tid & 63) == 0) { red[tid >> 6] = s; red[4 + (tid >> 6)] = s2; }
  __syncthreads();
  s = red[0] + red[1] + red[2] + red[3];
  s2 = red[4] + red[5] + red[6] + red[7];
  const float mean = s * (1.f / 1024.f);
  const float var = s2 * (1.f / 1024.f) - mean * mean;
  const float rstd = rsqrtf(var + 1e-5f);
  const float4 gv = ((const float4*)g)[tid];
  const float4 bv = ((const float4*)be)[tid];
  float4 of;
  of.x = (v.x - mean) * rstd * gv.x + bv.x;
  of.y = (v.y - mean) * rstd * gv.y + bv.y;
  of.z = (v.z - mean) * rstd * gv.z + bv.z;
  of.w = (v.w - mean) * rstd * gv.w + bv.w;
  if (fout) {
    ((float4*)(fout + (size_t)row * 1024))[tid] = of;
  } else {
    bf16x4 o4;
    o4[0] = (bf16)of.x; o4[1] = (bf16)of.y; o4[2] = (bf16)of.z; o4[3] = (bf16)of.w;
    *(bf16x4*)&xo[(size_t)row * 1024 + tid * 4] = o4;
  }
}

// ------------------------------ LayerNorm (fp32 y) --------------------------
__global__ __launch_bounds__(256) void ln_kernel(const float* __restrict__ y,
                                                 const float* __restrict__ g,
                                                 const float* __restrict__ be,
                                                 bf16* __restrict__ xo) {
  const int row = blockIdx.x, tid = threadIdx.x;
  const float4 v = ((const float4*)(y + (size_t)row * 1024))[tid];
  float s = v.x + v.y + v.z + v.w;
  float s2 = v.x * v.x + v.y * v.y + v.z * v.z + v.w * v.w;
#pragma unroll
  for (int o = 32; o > 0; o >>= 1) { s += __shfl_down(s, o); s2 += __shfl_down(s2, o); }
  __shared__ float red[8];
  if ((tid & 63) == 0) { red[tid >> 6] = s; red[4 + (tid >> 6)] = s2; }
  __syncthreads();
  s = red[0] + red[1] + red[2] + red[3];
  s2 = red[4] + red[5] + red[6] + red[7];
  const float mean = s * (1.f / 1024.f);
  const float var = s2 * (1.f / 1024.f) - mean * mean;
  const float rstd = rsqrtf(var + 1e-5f);
  const float4 gv = ((const float4*)g)[tid];
  const float4 bv = ((const float4*)be)[tid];
  bf16x4 o4;
  o4[0] = (bf16)((v.x - mean) * rstd * gv.x + bv.x);
  o4[1] = (bf16)((v.y - mean) * rstd * gv.y + bv.y);
  o4[2] = (bf16)((v.z - mean) * rstd * gv.z + bv.z);
  o4[3] = (bf16)((v.w - mean) * rstd * gv.w + bv.w);
  *(bf16x4*)&xo[(size_t)row * 1024 + tid * 4] = o4;
}

// ----------------------------------------------------------------------------
extern "C" void kernel_launch(void* const* d_in, const int* in_sizes, int n_in,
                              void* d_out, int out_size, void* d_ws, size_t ws_size,
                              hipStream_t stream) {
  const int* tokens = (const int*)d_in[0];
  const float* emb = (const float*)d_in[2];
  const float* Wq = (const float*)d_in[3];
  const float* bq = (const float*)d_in[4];
  const float* Wk = (const float*)d_in[5];
  const float* bk = (const float*)d_in[6];
  const float* Wv = (const float*)d_in[7];
  const float* bv = (const float*)d_in[8];
  const float* Wo = (const float*)d_in[9];
  const float* bo = (const float*)d_in[10];
  const float* W1 = (const float*)d_in[11];
  const float* b1 = (const float*)d_in[12];
  const float* W2 = (const float*)d_in[13];
  const float* b2 = (const float*)d_in[14];
  const float* g1 = (const float*)d_in[15];
  const float* be1 = (const float*)d_in[16];
  const float* g2 = (const float*)d_in[17];
  const float* be2 = (const float*)d_in[18];

  char* p = (char*)d_ws;
  auto carve = [&](size_t bytes) { char* r = p; p += (bytes + 255) & ~(size_t)255; return r; };
  bf16* wt_qkv = (bf16*)carve((size_t)3072 * 1024 * 2);
  bf16* wt_o   = (bf16*)carve((size_t)1024 * 1024 * 2);
  bf16* wt_1   = (bf16*)carve((size_t)4096 * 1024 * 2);
  bf16* wt_2   = (bf16*)carve((size_t)1024 * 4096 * 2);
  bf16* xb     = (bf16*)carve((size_t)4096 * 1024 * 2);
  bf16* qb     = (bf16*)carve((size_t)4096 * 1024 * 2);
  bf16* kb     = (bf16*)carve((size_t)4096 * 1024 * 2);
  bf16* vtb    = (bf16*)carve((size_t)4096 * 1024 * 2);
  bf16* ctxb   = (bf16*)carve((size_t)4096 * 1024 * 2);
  float* yb    = (float*)carve((size_t)4096 * 1024 * 4);
  float* pb    = (float*)carve((size_t)4 * 4096 * 1024 * 4);   // split-K partials
  bf16* hb     = (bf16*)carve((size_t)4096 * 4096 * 2);

  embed_kernel<<<4096, 256, 0, stream>>>(tokens, emb, xb);

  for (int l = 0; l < 6; ++l) {
    // 64x64 tiles: jobs sized (K/64)*(N/64)
    TArgs ta;
    ta.j[0] = { Wq + (size_t)l * 1024 * 1024, wt_qkv,                  1024, 1024, 0 };
    ta.j[1] = { Wk + (size_t)l * 1024 * 1024, wt_qkv + 1024 * 1024,    1024, 1024, 256 };
    ta.j[2] = { Wv + (size_t)l * 1024 * 1024, wt_qkv + 2 * 1024 * 1024,1024, 1024, 512 };
    ta.j[3] = { Wo + (size_t)l * 1024 * 1024, wt_o,                    1024, 1024, 768 };
    ta.j[4] = { W1 + (size_t)l * 1024 * 4096, wt_1,                    1024, 4096, 1024 };
    ta.j[5] = { W2 + (size_t)l * 4096 * 1024, wt_2,                    4096, 1024, 2048 };
    wtrans_kernel<<<3072, 256, 0, stream>>>(ta);

    // QKV: 256x192 tile, nbx = 16 -> grid 256 = 1 block/CU. V written
    // directly transposed into vtb (vtrans fused).
    gemm256<0, 3><<<256, 512, 0, stream>>>(xb, wt_qkv, 1024, 1024, 3072, 16,
        bq + (size_t)l * 1024, bk + (size_t)l * 1024, bv + (size_t)l * 1024,
        nullptr, nullptr, qb, kb, vtb);

    // attn: 16-wave blocks, Q=256, grid 256
    attn_kernel<<<256, 1024, 0, stream>>>(qb, kb, vtb, ctxb);

    // O-proj: 128^2 pipeline, single-pass K=1024, grid 256
    gemm128p<<<256, 256, 0, stream>>>(ctxb, wt_o, 1024,
        bo + (size_t)l * 1024, xb, yb);
    ln_kernel<<<4096, 256, 0, stream>>>(yb, g1 + (size_t)l * 1024,
        be1 + (size_t)l * 1024, xb);

    // FFN1: 256^2 tile, grid 16x16 = 256
    gemm256<2, 4><<<256, 512, 0, stream>>>(xb, wt_1, 1024, 1024, 4096, 16,
        b1 + (size_t)l * 4096, nullptr, nullptr, hb,
        nullptr, nullptr, nullptr, nullptr);

    // FFN2: 256^2 tile split-K=4 (K-slice 1024), grid (64,4) = 256 blocks
    gemm256<1, 4><<<dim3(64, 4), 512, 0, stream>>>(hb, wt_2, 4096, 1024, 1024, 4,
        nullptr, nullptr, nullptr, nullptr, pb,
        nullptr, nullptr, nullptr);
    ln2_kernel<4><<<4096, 256, 0, stream>>>(pb, xb, b2 + (size_t)l * 1024,
        g2 + (size_t)l * 1024, be2 + (size_t)l * 1024, xb,
        (l == 5) ? (float*)d_out : nullptr);
  }
}